// Round 7
// baseline (462.496 us; speedup 1.0000x reference)
//
#include <hip/hip_runtime.h>
#include <hip/hip_bf16.h>

#define NB 16
#define NVEC 2048
#define NDIM 32
#define NW 4
#define NHID 128
#define NCLASS 10
#define PITCH 132                 // padded 129 (k and p dims)
#define CTSLOT (PITCH * PITCH)    // 17424 floats per (l,b)
#define CTTOT (NW * NB * CTSLOT)  // 1,115,136 floats
#define ZSLOT (129 * 32)          // 4128

// tanh-approx GELU; validated absmax ~1e-3 vs exact-erf ref (R5/R6).
__device__ __forceinline__ float gelu_fast(float x) {
    float t = 1.5957691216057308f * x * (1.0f + 0.044715f * x * x);
    return x / (1.0f + __expf(-t));
}

// ---------------------------------------------------------------------------
// X = emb[data]; CT = 0; out = bias. 4096 blocks.
__global__ __launch_bounds__(256) void k_embed(const int* __restrict__ data,
                                               const float* __restrict__ emb,
                                               const float* __restrict__ bf,
                                               float* __restrict__ X,
                                               float* __restrict__ CT,
                                               float* __restrict__ out) {
    int gid = blockIdx.x * 256 + threadIdx.x;   // < 1048576
    int row = gid >> 5, d = gid & 31;
    X[gid] = emb[data[row] * NDIM + d];
    for (int i = gid; i < CTTOT; i += NB * NVEC * NDIM) CT[i] = 0.f;
    if (blockIdx.x == 0 && threadIdx.x < NB * NCLASS)
        out[threadIdx.x] = bf[threadIdx.x % NCLASS];
}

// ---------------------------------------------------------------------------
// C_l[b] = B_l @ A_{l+1}[b]  (129x129), l=0..2;  l=3: T = B_3 @ X (129x32).
// B_l = [fw2_l (128x2048); fb2_l^T].  A = [h_{l+1}, 1] with h computed on the
// fly from X;  l=3: A = X zero-padded to 129 cols (aug col = 0).
// Storage transposed: CT[l][b][p][k] = C[k][p]  (k<129 real; cols 129..131
// stay 0 from k_embed).  Split-m partials accumulated via atomicAdd.
// grid (8 ms, NB, NW); 256 thr; 8x8 register tile over (j,k) in [0,128)^2.
__global__ __launch_bounds__(256, 2) void k_C(const float* __restrict__ X,
                                              const float* __restrict__ fw1,
                                              const float* __restrict__ fb1,
                                              const float* __restrict__ fw2,
                                              const float* __restrict__ fb2,
                                              float* __restrict__ CT) {
    __shared__ float w1s[NDIM * NHID];   // 16 KB (h-layer weights)
    __shared__ float Xs[32 * 36];        // 4.6 KB
    __shared__ float As[32 * PITCH];     // 16.9 KB  [mm][j]
    __shared__ float Bs[32 * PITCH];     // 16.9 KB  [mm][k]
    int ms = blockIdx.x, b = blockIdx.y, l = blockIdx.z;
    int tid = threadIdx.x;
    bool hasH = (l < 3);

    const float* fw2l = fw2 + (size_t)l * NHID * NVEC;
    const float* fb2l = fb2 + (size_t)l * NVEC;
    const float* fw1n = fw1 + (size_t)(l + 1) * NDIM * NHID;  // valid when hasH
    const float* fb1n = fb1 + (size_t)(l + 1) * NHID;

    float hbias[16];
    if (hasH) {
#pragma unroll
        for (int j = 0; j < 4; ++j)
            ((float4*)w1s)[tid + j * 256] = ((const float4*)fw1n)[tid + j * 256];
        int jb = (tid & 7) * 16;
#pragma unroll
        for (int jj = 0; jj < 16; ++jj) hbias[jj] = fb1n[jb + jj];
    }

    int tk = tid & 15, tj = tid >> 4;
    int k0 = tk * 8, j0 = tj * 8;
    float acc[8][8];
#pragma unroll
    for (int jj = 0; jj < 8; ++jj)
#pragma unroll
        for (int kk = 0; kk < 8; ++kk) acc[jj][kk] = 0.f;
    float eR = 0.f, eC = 0.f;

    for (int s = 0; s < 8; ++s) {
        int mbase = ms * 256 + s * 32;
        __syncthreads();                 // protect As/Bs/Xs from prior readers
        {   // stage Xs [mm][d] pitch 36
            float4 v = ((const float4*)(X + ((size_t)b * NVEC + mbase) * NDIM))[tid];
            int mm = tid >> 3, d4 = (tid & 7) * 4;
            Xs[mm * 36 + d4] = v.x; Xs[mm * 36 + d4 + 1] = v.y;
            Xs[mm * 36 + d4 + 2] = v.z; Xs[mm * 36 + d4 + 3] = v.w;
        }
#pragma unroll
        for (int j = 0; j < 4; ++j) {    // stage Bs [mm][k]: 128x32 tile of fw2
            int i4 = tid + j * 256;      // 1024 float4s
            int k = i4 >> 3, mm4 = (i4 & 7) * 4;
            float4 w = *(const float4*)&fw2l[(size_t)k * NVEC + mbase + mm4];
            Bs[(mm4 + 0) * PITCH + k] = w.x;
            Bs[(mm4 + 1) * PITCH + k] = w.y;
            Bs[(mm4 + 2) * PITCH + k] = w.z;
            Bs[(mm4 + 3) * PITCH + k] = w.w;
        }
        if (tid < 32) {
            Bs[tid * PITCH + 128] = fb2l[mbase + tid];
            Bs[tid * PITCH + 129] = 0.f;
            Bs[tid * PITCH + 130] = 0.f;
            Bs[tid * PITCH + 131] = 0.f;
        }
        __syncthreads();                 // Xs ready for h-compute

        {   // build As: h (l<3) or X padded (l=3); thread: 1 mm x 16 j
            int mm = tid >> 3, jb = (tid & 7) * 16;
            if (hasH) {
                float ha[16];
#pragma unroll
                for (int jj = 0; jj < 16; ++jj) ha[jj] = hbias[jj];
#pragma unroll 8
                for (int d = 0; d < NDIM; ++d) {
                    float x = Xs[mm * 36 + d];
                    float4 w0 = *(const float4*)&w1s[d * NHID + jb];
                    float4 w1 = *(const float4*)&w1s[d * NHID + jb + 4];
                    float4 w2 = *(const float4*)&w1s[d * NHID + jb + 8];
                    float4 w3 = *(const float4*)&w1s[d * NHID + jb + 12];
                    float wv[16] = {w0.x, w0.y, w0.z, w0.w, w1.x, w1.y, w1.z, w1.w,
                                    w2.x, w2.y, w2.z, w2.w, w3.x, w3.y, w3.z, w3.w};
#pragma unroll
                    for (int jj = 0; jj < 16; ++jj) ha[jj] += x * wv[jj];
                }
#pragma unroll
                for (int jj = 0; jj < 16; ++jj)
                    As[mm * PITCH + jb + jj] = gelu_fast(ha[jj]);
            } else {
#pragma unroll
                for (int jj = 0; jj < 16; ++jj) {
                    int j = jb + jj;
                    As[mm * PITCH + j] = (j < NDIM) ? Xs[mm * 36 + j] : 0.f;
                }
            }
            if (tid < 32) {
                As[tid * PITCH + 128] = hasH ? 1.f : 0.f;   // aug column
                As[tid * PITCH + 129] = 0.f;
                As[tid * PITCH + 130] = 0.f;
                As[tid * PITCH + 131] = 0.f;
            }
        }
        __syncthreads();                 // As ready

        // main gemm: C[k][j] += B[k][mm]*A[mm][j]
#pragma unroll 4
        for (int mm = 0; mm < 32; ++mm) {
            float4 a0 = *(const float4*)&As[mm * PITCH + j0];
            float4 a1 = *(const float4*)&As[mm * PITCH + j0 + 4];
            float4 b0 = *(const float4*)&Bs[mm * PITCH + k0];
            float4 b1 = *(const float4*)&Bs[mm * PITCH + k0 + 4];
            float av[8] = {a0.x, a0.y, a0.z, a0.w, a1.x, a1.y, a1.z, a1.w};
            float bv[8] = {b0.x, b0.y, b0.z, b0.w, b1.x, b1.y, b1.z, b1.w};
#pragma unroll
            for (int jj = 0; jj < 8; ++jj)
#pragma unroll
                for (int kk = 0; kk < 8; ++kk) acc[jj][kk] += av[jj] * bv[kk];
        }
        // edges: row k=128 (B=fb2) over all j; col j=128 (A=aug) over k<128
        if (tid < 132) {
#pragma unroll 8
            for (int mm = 0; mm < 32; ++mm)
                eR += Bs[mm * PITCH + 128] * As[mm * PITCH + tid];
        }
        if (tid >= 124 && tid < 252) {
            int ke = tid - 124;
#pragma unroll 8
            for (int mm = 0; mm < 32; ++mm)
                eC += Bs[mm * PITCH + ke] * As[mm * PITCH + 128];
        }
    }

    float* ct = CT + (size_t)(l * NB + b) * CTSLOT;
#pragma unroll
    for (int jj = 0; jj < 8; ++jj)
#pragma unroll
        for (int kk = 0; kk < 8; ++kk)
            atomicAdd(&ct[(j0 + jj) * PITCH + k0 + kk], acc[jj][kk]);
    if (tid < 132) atomicAdd(&ct[tid * PITCH + 128], eR);           // CT[p=t][k=128]
    if (tid >= 124 && tid < 252) atomicAdd(&ct[128 * PITCH + (tid - 124)], eC);
}

// ---------------------------------------------------------------------------
// Z = C_0 @ C_1 @ C_2 @ T per b, chained right-to-left in LDS.
// grid (4 jg, NB), 192 thr (active t<132 = one output row each, 8 j-cols).
__global__ __launch_bounds__(192) void k_Z(const float* __restrict__ CT,
                                           float* __restrict__ Zbuf) {
    __shared__ float Zp[2][PITCH * 8];
    int jg = blockIdx.x, b = blockIdx.y;
    int t = threadIdx.x;
    int j0 = jg * 8;

    const float* ct3 = CT + (size_t)(3 * NB + b) * CTSLOT;
    if (t < PITCH) {
#pragma unroll
        for (int jj = 0; jj < 8; ++jj)
            Zp[0][t * 8 + jj] = ct3[(j0 + jj) * PITCH + t];   // Tin[p][jj]
    }
    __syncthreads();

    int cur = 0;
    for (int l = 2; l >= 0; --l) {
        const float* ctl = CT + (size_t)(l * NB + b) * CTSLOT;
        float acc[8] = {0.f, 0.f, 0.f, 0.f, 0.f, 0.f, 0.f, 0.f};
        if (t < PITCH) {
#pragma unroll 4
            for (int p = 0; p < 129; ++p) {
                float cv = ctl[p * PITCH + t];                // coalesced over t
                float4 z0 = *(const float4*)&Zp[cur][p * 8];  // broadcast
                float4 z1 = *(const float4*)&Zp[cur][p * 8 + 4];
                acc[0] += cv * z0.x; acc[1] += cv * z0.y;
                acc[2] += cv * z0.z; acc[3] += cv * z0.w;
                acc[4] += cv * z1.x; acc[5] += cv * z1.y;
                acc[6] += cv * z1.z; acc[7] += cv * z1.w;
            }
        }
        __syncthreads();
        if (t < PITCH) {
            *(float4*)&Zp[1 - cur][t * 8] = make_float4(acc[0], acc[1], acc[2], acc[3]);
            *(float4*)&Zp[1 - cur][t * 8 + 4] = make_float4(acc[4], acc[5], acc[6], acc[7]);
        }
        __syncthreads();
        cur ^= 1;
    }
    if (t < 129) {
        *(float4*)&Zbuf[(size_t)b * ZSLOT + t * 32 + j0] =
            make_float4(Zp[cur][t * 8], Zp[cur][t * 8 + 1], Zp[cur][t * 8 + 2], Zp[cur][t * 8 + 3]);
        *(float4*)&Zbuf[(size_t)b * ZSLOT + t * 32 + j0 + 4] =
            make_float4(Zp[cur][t * 8 + 4], Zp[cur][t * 8 + 5], Zp[cur][t * 8 + 6], Zp[cur][t * 8 + 7]);
    }
}

// ---------------------------------------------------------------------------
// out[b,c] += sum_n sum_d V[n,d] * Wf[n*32+d, c],
//   V[n,:] = h_0[n,:] @ Z[0:128,:] + Z[128,:],  h_0 from X on the fly.
// grid (16 nc, NB); 256 thr; 128 n-rows per block in 4 subtiles of 32.
__global__ __launch_bounds__(256, 2) void k_out(const float* __restrict__ X,
                                                const float* __restrict__ fw1,
                                                const float* __restrict__ fb1,
                                                const float* __restrict__ Zbuf,
                                                const float* __restrict__ Wf,
                                                float* __restrict__ out) {
    __shared__ float w1s[NDIM * NHID];   // 16 KB (fw1[0])
    __shared__ float Zs[PITCH * 36];     // [k][d] pitch 36
    __shared__ float Xs[32 * 36];
    __shared__ float hs[32 * 133];       // pitch 133: conflict-free r-lanes
    __shared__ float vs[32 * 33];
    __shared__ float red[4][NCLASS];
    int nc = blockIdx.x, b = blockIdx.y;
    int tid = threadIdx.x;

#pragma unroll
    for (int j = 0; j < 4; ++j)
        ((float4*)w1s)[tid + j * 256] = ((const float4*)fw1)[tid + j * 256];
    for (int i = tid; i < ZSLOT; i += 256) {
        int k = i >> 5, d = i & 31;
        Zs[k * 36 + d] = Zbuf[(size_t)b * ZSLOT + i];
    }
    float hbias[16];
    {
        int jb = (tid & 7) * 16;
#pragma unroll
        for (int jj = 0; jj < 16; ++jj) hbias[jj] = fb1[jb + jj];
    }

    float acc[NCLASS];
#pragma unroll
    for (int c = 0; c < NCLASS; ++c) acc[c] = 0.f;

    for (int ss = 0; ss < 4; ++ss) {
        int n0 = nc * 128 + ss * 32;
        __syncthreads();                 // protect Xs/hs/vs (+Zs/w1s at ss=0)
        {
            float4 v = ((const float4*)(X + ((size_t)b * NVEC + n0) * NDIM))[tid];
            int mm = tid >> 3, d4 = (tid & 7) * 4;
            Xs[mm * 36 + d4] = v.x; Xs[mm * 36 + d4 + 1] = v.y;
            Xs[mm * 36 + d4 + 2] = v.z; Xs[mm * 36 + d4 + 3] = v.w;
        }
        __syncthreads();
        {   // h_0 tile: 1 mm x 16 k per thread
            int mm = tid >> 3, jb = (tid & 7) * 16;
            float ha[16];
#pragma unroll
            for (int jj = 0; jj < 16; ++jj) ha[jj] = hbias[jj];
#pragma unroll 8
            for (int d = 0; d < NDIM; ++d) {
                float x = Xs[mm * 36 + d];
                float4 w0 = *(const float4*)&w1s[d * NHID + jb];
                float4 w1 = *(const float4*)&w1s[d * NHID + jb + 4];
                float4 w2 = *(const float4*)&w1s[d * NHID + jb + 8];
                float4 w3 = *(const float4*)&w1s[d * NHID + jb + 12];
                float wv[16] = {w0.x, w0.y, w0.z, w0.w, w1.x, w1.y, w1.z, w1.w,
                                w2.x, w2.y, w2.z, w2.w, w3.x, w3.y, w3.z, w3.w};
#pragma unroll
                for (int jj = 0; jj < 16; ++jj) ha[jj] += x * wv[jj];
            }
#pragma unroll
            for (int jj = 0; jj < 16; ++jj)
                hs[mm * 133 + jb + jj] = gelu_fast(ha[jj]);
        }
        __syncthreads();
        {   // V tile: thread (r = tid&31, d0 = (tid>>5)*4)
            int r = tid & 31, d0 = (tid >> 5) * 4;
            float4 a = *(const float4*)&Zs[128 * 36 + d0];
#pragma unroll 8
            for (int k = 0; k < NHID; ++k) {
                float h = hs[r * 133 + k];
                float4 z = *(const float4*)&Zs[k * 36 + d0];
                a.x += h * z.x; a.y += h * z.y; a.z += h * z.z; a.w += h * z.w;
            }
            vs[r * 33 + d0] = a.x; vs[r * 33 + d0 + 1] = a.y;
            vs[r * 33 + d0 + 2] = a.z; vs[r * 33 + d0 + 3] = a.w;
        }
        __syncthreads();
        {   // Wf projection: 4 (r,d) pairs per thread
#pragma unroll
            for (int i = 0; i < 4; ++i) {
                int q = tid + i * 256;
                int r = q >> 5, d = q & 31;
                float v = vs[r * 33 + d];
                const float* wr = Wf + ((size_t)(n0 + r) * NDIM + d) * NCLASS;
#pragma unroll
                for (int c = 0; c < NCLASS; ++c) acc[c] += v * wr[c];
            }
        }
    }

    // reduce acc over block: wave shuffle then 4-wave LDS
#pragma unroll
    for (int off = 32; off >= 1; off >>= 1)
#pragma unroll
        for (int c = 0; c < NCLASS; ++c) acc[c] += __shfl_down(acc[c], off);
    if ((tid & 63) == 0) {
#pragma unroll
        for (int c = 0; c < NCLASS; ++c) red[tid >> 6][c] = acc[c];
    }
    __syncthreads();
    if (tid < NCLASS)
        atomicAdd(&out[b * NCLASS + tid],
                  red[0][tid] + red[1][tid] + red[2][tid] + red[3][tid]);
}

// ---------------------------------------------------------------------------
extern "C" void kernel_launch(void* const* d_in, const int* in_sizes, int n_in,
                              void* d_out, int out_size, void* d_ws, size_t ws_size,
                              hipStream_t stream) {
    const int*   data = (const int*)d_in[0];
    const float* emb  = (const float*)d_in[1];
    const float* fw1  = (const float*)d_in[2];
    const float* fb1  = (const float*)d_in[3];
    const float* fw2  = (const float*)d_in[4];
    const float* fb2  = (const float*)d_in[5];
    const float* Wf   = (const float*)d_in[6];
    const float* bf   = (const float*)d_in[7];
    float* out = (float*)d_out;

    float* X    = (float*)d_ws;               // 1,048,576 f
    float* CT   = X + NB * NVEC * NDIM;       // 1,115,136 f
    float* Zbuf = CT + CTTOT;                 // 66,048 f

    k_embed<<<dim3((NB * NVEC * NDIM) / 256), 256, 0, stream>>>(data, emb, bf, X, CT, out);
    k_C<<<dim3(8, NB, NW), 256, 0, stream>>>(X, fw1, fb1, fw2, fb2, CT);
    k_Z<<<dim3(4, NB), 192, 0, stream>>>(CT, Zbuf);
    k_out<<<dim3(16, NB), 256, 0, stream>>>(X, fw1, fb1, Zbuf, Wf, out);
}

// Round 8
// 265.273 us; speedup vs baseline: 1.7435x; 1.7435x over previous
//
#include <hip/hip_runtime.h>
#include <hip/hip_bf16.h>

#define NB 16
#define NVEC 2048
#define NDIM 32
#define NW 4
#define NHID 128
#define NCLASS 10
#define PITCH 132                 // padded 129 (k and p dims)
#define CTSLOT (PITCH * PITCH)    // 17424 floats per (l,b)
#define MSC 8                     // m-splits for k_C
#define ZSLOT (129 * 32)

// tanh-approx GELU; validated absmax ~1e-3 vs exact-erf ref (R5-R7).
__device__ __forceinline__ float gelu_fast(float x) {
    float t = 1.5957691216057308f * x * (1.0f + 0.044715f * x * x);
    return x / (1.0f + __expf(-t));
}

// ---------------------------------------------------------------------------
// X = emb[data]; out = bias. 4096 blocks.
__global__ __launch_bounds__(256) void k_embed(const int* __restrict__ data,
                                               const float* __restrict__ emb,
                                               const float* __restrict__ bf,
                                               float* __restrict__ X,
                                               float* __restrict__ out) {
    int gid = blockIdx.x * 256 + threadIdx.x;   // < 1048576
    int row = gid >> 5, d = gid & 31;
    X[gid] = emb[data[row] * NDIM + d];
    if (blockIdx.x == 0 && threadIdx.x < NB * NCLASS)
        out[threadIdx.x] = bf[threadIdx.x % NCLASS];
}

// ---------------------------------------------------------------------------
// Partial C_l[b] = B_l @ A_{l+1}[b] over 256 m's. PLAIN stores to CTpart
// (R7's atomicAdd path generated 264 MB of RMW traffic -> 317 us; stores are
// 36 MB coalesced). grid (MSC, NB, NW); 256 thr; 8x8 register tile; thread's
// k-set {tk*4+q, 64+tk*4+q} -> quarter-wave reads contiguous (2-way, free).
__global__ __launch_bounds__(256, 3) void k_C(const float* __restrict__ X,
                                              const float* __restrict__ fw1,
                                              const float* __restrict__ fb1,
                                              const float* __restrict__ fw2,
                                              const float* __restrict__ fb2,
                                              float* __restrict__ CTpart) {
    __shared__ float w1s[NDIM * NHID];   // 16 KB
    __shared__ float Xs[32 * 33];        // 4.1 KB
    __shared__ float As[32 * PITCH];     // 16.5 KB  [mm][j]
    __shared__ float Bs[32 * PITCH];     // 16.5 KB  [mm][k]
    int ms = blockIdx.x, b = blockIdx.y, l = blockIdx.z;
    int tid = threadIdx.x;
    bool hasH = (l < 3);

    const float* fw2l = fw2 + (size_t)l * NHID * NVEC;
    const float* fb2l = fb2 + (size_t)l * NVEC;
    const float* fw1n = fw1 + (size_t)(l + 1) * NDIM * NHID;
    const float* fb1n = fb1 + (size_t)(l + 1) * NHID;

    float hbias[16];
    if (hasH) {
#pragma unroll
        for (int j = 0; j < 4; ++j)
            ((float4*)w1s)[tid + j * 256] = ((const float4*)fw1n)[tid + j * 256];
        int jb = (tid & 7) * 16;
#pragma unroll
        for (int jj = 0; jj < 16; ++jj) hbias[jj] = fb1n[jb + jj];
    }

    int tk = tid & 15, tj = tid >> 4;
    int kA = tk * 4, kB = 64 + tk * 4, j0 = tj * 8;
    float acc[8][8];
#pragma unroll
    for (int jj = 0; jj < 8; ++jj)
#pragma unroll
        for (int kk = 0; kk < 8; ++kk) acc[jj][kk] = 0.f;
    float eR = 0.f, eC = 0.f;

    for (int s = 0; s < 8; ++s) {
        int mbase = ms * 256 + s * 32;
        __syncthreads();                 // protect As/Bs/Xs from prior readers
        {   // stage Xs [mm][d] pitch 33
            float4 v = ((const float4*)(X + ((size_t)b * NVEC + mbase) * NDIM))[tid];
            int mm = tid >> 3, d4 = (tid & 7) * 4;
            Xs[mm * 33 + d4] = v.x; Xs[mm * 33 + d4 + 1] = v.y;
            Xs[mm * 33 + d4 + 2] = v.z; Xs[mm * 33 + d4 + 3] = v.w;
        }
#pragma unroll
        for (int j = 0; j < 4; ++j) {    // stage Bs [mm][k]: 128x32 tile of fw2
            int i4 = tid + j * 256;
            int k = i4 >> 3, mm4 = (i4 & 7) * 4;
            float4 w = *(const float4*)&fw2l[(size_t)k * NVEC + mbase + mm4];
            Bs[(mm4 + 0) * PITCH + k] = w.x;
            Bs[(mm4 + 1) * PITCH + k] = w.y;
            Bs[(mm4 + 2) * PITCH + k] = w.z;
            Bs[(mm4 + 3) * PITCH + k] = w.w;
        }
        if (tid < 32) {
            Bs[tid * PITCH + 128] = fb2l[mbase + tid];
            Bs[tid * PITCH + 129] = 0.f;
            Bs[tid * PITCH + 130] = 0.f;
            Bs[tid * PITCH + 131] = 0.f;
        }
        __syncthreads();                 // Xs ready

        {   // build As: h (l<3) or X padded (l=3); 1 mm x 16 j per thread
            int mm = tid >> 3, jb = (tid & 7) * 16;
            if (hasH) {
                float ha[16];
#pragma unroll
                for (int jj = 0; jj < 16; ++jj) ha[jj] = hbias[jj];
#pragma unroll 8
                for (int d = 0; d < NDIM; ++d) {
                    float x = Xs[mm * 33 + d];
                    float4 w0 = *(const float4*)&w1s[d * NHID + jb];
                    float4 w1 = *(const float4*)&w1s[d * NHID + jb + 4];
                    float4 w2 = *(const float4*)&w1s[d * NHID + jb + 8];
                    float4 w3 = *(const float4*)&w1s[d * NHID + jb + 12];
                    float wv[16] = {w0.x, w0.y, w0.z, w0.w, w1.x, w1.y, w1.z, w1.w,
                                    w2.x, w2.y, w2.z, w2.w, w3.x, w3.y, w3.z, w3.w};
#pragma unroll
                    for (int jj = 0; jj < 16; ++jj) ha[jj] += x * wv[jj];
                }
#pragma unroll
                for (int jj = 0; jj < 16; ++jj)
                    As[mm * PITCH + jb + jj] = gelu_fast(ha[jj]);
            } else {
#pragma unroll
                for (int jj = 0; jj < 16; ++jj) {
                    int j = jb + jj;
                    As[mm * PITCH + j] = (j < NDIM) ? Xs[mm * 33 + j] : 0.f;
                }
            }
            if (tid < 32) {
                As[tid * PITCH + 128] = hasH ? 1.f : 0.f;
                As[tid * PITCH + 129] = 0.f;
                As[tid * PITCH + 130] = 0.f;
                As[tid * PITCH + 131] = 0.f;
            }
        }
        __syncthreads();                 // As ready

        // main gemm: C[k][j] += B[k][mm]*A[mm][j]
#pragma unroll 4
        for (int mm = 0; mm < 32; ++mm) {
            float4 a0 = *(const float4*)&As[mm * PITCH + j0];       // broadcast
            float4 a1 = *(const float4*)&As[mm * PITCH + j0 + 4];
            float4 b0 = *(const float4*)&Bs[mm * PITCH + kA];       // contiguous
            float4 b1 = *(const float4*)&Bs[mm * PITCH + kB];
            float av[8] = {a0.x, a0.y, a0.z, a0.w, a1.x, a1.y, a1.z, a1.w};
            float bv[8] = {b0.x, b0.y, b0.z, b0.w, b1.x, b1.y, b1.z, b1.w};
#pragma unroll
            for (int jj = 0; jj < 8; ++jj)
#pragma unroll
                for (int kk = 0; kk < 8; ++kk) acc[jj][kk] += av[jj] * bv[kk];
        }
        // edges: row k=128 (B=fb2) over all j; col j=128 over k<128
        if (tid < 132) {
#pragma unroll 8
            for (int mm = 0; mm < 32; ++mm)
                eR += Bs[mm * PITCH + 128] * As[mm * PITCH + tid];
        }
        if (tid >= 124 && tid < 252) {
            int ke = tid - 124;
#pragma unroll 8
            for (int mm = 0; mm < 32; ++mm)
                eC += Bs[mm * PITCH + ke] * As[mm * PITCH + 128];
        }
    }

    float* ct = CTpart + ((size_t)ms * NW * NB + (size_t)l * NB + b) * CTSLOT;
#pragma unroll
    for (int jj = 0; jj < 8; ++jj) {
        *(float4*)&ct[(j0 + jj) * PITCH + kA] =
            make_float4(acc[jj][0], acc[jj][1], acc[jj][2], acc[jj][3]);
        *(float4*)&ct[(j0 + jj) * PITCH + kB] =
            make_float4(acc[jj][4], acc[jj][5], acc[jj][6], acc[jj][7]);
    }
    if (tid < 132) ct[tid * PITCH + 128] = eR;
    if (tid >= 124 && tid < 252) ct[128 * PITCH + (tid - 124)] = eC;
}

// ---------------------------------------------------------------------------
// CT[slot][p][k] = sum_ms CTpart[ms][slot][p][k] (k<129), 0 for pad k=129..131.
// Domain: 64 slots x 129 p x 132 k = 1,089,792 = 4257 * 256 exactly.
__global__ __launch_bounds__(256) void k_Cred(const float* __restrict__ CTpart,
                                              float* __restrict__ CT) {
    int gid = blockIdx.x * 256 + threadIdx.x;
    int slot = gid / (129 * PITCH);
    int r = gid - slot * (129 * PITCH);
    int p = r / PITCH, k = r - p * PITCH;
    float s = 0.f;
    if (k < 129) {
        const float* base = CTpart + (size_t)slot * CTSLOT + p * PITCH + k;
#pragma unroll
        for (int ms = 0; ms < MSC; ++ms)
            s += base[(size_t)ms * (NW * NB) * CTSLOT];
    }
    CT[(size_t)slot * CTSLOT + p * PITCH + k] = s;
}

// ---------------------------------------------------------------------------
// Z = C_0 @ C_1 @ C_2 @ T per b, chained right-to-left in LDS.
// grid (4 jg, NB), 192 thr.
__global__ __launch_bounds__(192) void k_Z(const float* __restrict__ CT,
                                           float* __restrict__ Zbuf) {
    __shared__ float Zp[2][PITCH * 8];
    int jg = blockIdx.x, b = blockIdx.y;
    int t = threadIdx.x;
    int j0 = jg * 8;

    const float* ct3 = CT + (size_t)(3 * NB + b) * CTSLOT;
    if (t < PITCH) {
#pragma unroll
        for (int jj = 0; jj < 8; ++jj)
            Zp[0][t * 8 + jj] = ct3[(j0 + jj) * PITCH + t];
    }
    __syncthreads();

    int cur = 0;
    for (int l = 2; l >= 0; --l) {
        const float* ctl = CT + (size_t)(l * NB + b) * CTSLOT;
        float acc[8] = {0.f, 0.f, 0.f, 0.f, 0.f, 0.f, 0.f, 0.f};
        if (t < PITCH) {
#pragma unroll 4
            for (int p = 0; p < 129; ++p) {
                float cv = ctl[p * PITCH + t];
                float4 z0 = *(const float4*)&Zp[cur][p * 8];
                float4 z1 = *(const float4*)&Zp[cur][p * 8 + 4];
                acc[0] += cv * z0.x; acc[1] += cv * z0.y;
                acc[2] += cv * z0.z; acc[3] += cv * z0.w;
                acc[4] += cv * z1.x; acc[5] += cv * z1.y;
                acc[6] += cv * z1.z; acc[7] += cv * z1.w;
            }
        }
        __syncthreads();
        if (t < PITCH) {
            *(float4*)&Zp[1 - cur][t * 8] = make_float4(acc[0], acc[1], acc[2], acc[3]);
            *(float4*)&Zp[1 - cur][t * 8 + 4] = make_float4(acc[4], acc[5], acc[6], acc[7]);
        }
        __syncthreads();
        cur ^= 1;
    }
    if (t < 129) {
        *(float4*)&Zbuf[(size_t)b * ZSLOT + t * 32 + j0] =
            make_float4(Zp[cur][t * 8], Zp[cur][t * 8 + 1], Zp[cur][t * 8 + 2], Zp[cur][t * 8 + 3]);
        *(float4*)&Zbuf[(size_t)b * ZSLOT + t * 32 + j0 + 4] =
            make_float4(Zp[cur][t * 8 + 4], Zp[cur][t * 8 + 5], Zp[cur][t * 8 + 6], Zp[cur][t * 8 + 7]);
    }
}

// ---------------------------------------------------------------------------
// out[b,c] += sum_n,d (h_0[n,:]@Z[0:128,:] + Z[128,:])[d] * Wf[n*32+d, c]
// grid (16 nc, NB); 256 thr; 128 n-rows per block in 4 subtiles of 32.
__global__ __launch_bounds__(256, 2) void k_out(const float* __restrict__ X,
                                                const float* __restrict__ fw1,
                                                const float* __restrict__ fb1,
                                                const float* __restrict__ Zbuf,
                                                const float* __restrict__ Wf,
                                                float* __restrict__ out) {
    __shared__ float w1s[NDIM * NHID];
    __shared__ float Zs[PITCH * 36];
    __shared__ float Xs[32 * 36];
    __shared__ float hs[32 * 133];
    __shared__ float vs[32 * 33];
    __shared__ float red[4][NCLASS];
    int nc = blockIdx.x, b = blockIdx.y;
    int tid = threadIdx.x;

#pragma unroll
    for (int j = 0; j < 4; ++j)
        ((float4*)w1s)[tid + j * 256] = ((const float4*)fw1)[tid + j * 256];
    for (int i = tid; i < ZSLOT; i += 256) {
        int k = i >> 5, d = i & 31;
        Zs[k * 36 + d] = Zbuf[(size_t)b * ZSLOT + i];
    }
    float hbias[16];
    {
        int jb = (tid & 7) * 16;
#pragma unroll
        for (int jj = 0; jj < 16; ++jj) hbias[jj] = fb1[jb + jj];
    }

    float acc[NCLASS];
#pragma unroll
    for (int c = 0; c < NCLASS; ++c) acc[c] = 0.f;

    for (int ss = 0; ss < 4; ++ss) {
        int n0 = nc * 128 + ss * 32;
        __syncthreads();
        {
            float4 v = ((const float4*)(X + ((size_t)b * NVEC + n0) * NDIM))[tid];
            int mm = tid >> 3, d4 = (tid & 7) * 4;
            Xs[mm * 36 + d4] = v.x; Xs[mm * 36 + d4 + 1] = v.y;
            Xs[mm * 36 + d4 + 2] = v.z; Xs[mm * 36 + d4 + 3] = v.w;
        }
        __syncthreads();
        {   // h_0 tile
            int mm = tid >> 3, jb = (tid & 7) * 16;
            float ha[16];
#pragma unroll
            for (int jj = 0; jj < 16; ++jj) ha[jj] = hbias[jj];
#pragma unroll 8
            for (int d = 0; d < NDIM; ++d) {
                float x = Xs[mm * 36 + d];
                float4 w0 = *(const float4*)&w1s[d * NHID + jb];
                float4 w1 = *(const float4*)&w1s[d * NHID + jb + 4];
                float4 w2 = *(const float4*)&w1s[d * NHID + jb + 8];
                float4 w3 = *(const float4*)&w1s[d * NHID + jb + 12];
                float wv[16] = {w0.x, w0.y, w0.z, w0.w, w1.x, w1.y, w1.z, w1.w,
                                w2.x, w2.y, w2.z, w2.w, w3.x, w3.y, w3.z, w3.w};
#pragma unroll
                for (int jj = 0; jj < 16; ++jj) ha[jj] += x * wv[jj];
            }
#pragma unroll
            for (int jj = 0; jj < 16; ++jj)
                hs[mm * 133 + jb + jj] = gelu_fast(ha[jj]);
        }
        __syncthreads();
        {   // V tile
            int r = tid & 31, d0 = (tid >> 5) * 4;
            float4 a = *(const float4*)&Zs[128 * 36 + d0];
#pragma unroll 8
            for (int k = 0; k < NHID; ++k) {
                float h = hs[r * 133 + k];
                float4 z = *(const float4*)&Zs[k * 36 + d0];
                a.x += h * z.x; a.y += h * z.y; a.z += h * z.z; a.w += h * z.w;
            }
            vs[r * 33 + d0] = a.x; vs[r * 33 + d0 + 1] = a.y;
            vs[r * 33 + d0 + 2] = a.z; vs[r * 33 + d0 + 3] = a.w;
        }
        __syncthreads();
        {   // Wf projection
#pragma unroll
            for (int i = 0; i < 4; ++i) {
                int q = tid + i * 256;
                int r = q >> 5, d = q & 31;
                float v = vs[r * 33 + d];
                const float* wr = Wf + ((size_t)(n0 + r) * NDIM + d) * NCLASS;
#pragma unroll
                for (int c = 0; c < NCLASS; ++c) acc[c] += v * wr[c];
            }
        }
    }

#pragma unroll
    for (int off = 32; off >= 1; off >>= 1)
#pragma unroll
        for (int c = 0; c < NCLASS; ++c) acc[c] += __shfl_down(acc[c], off);
    if ((tid & 63) == 0) {
#pragma unroll
        for (int c = 0; c < NCLASS; ++c) red[tid >> 6][c] = acc[c];
    }
    __syncthreads();
    if (tid < NCLASS)
        atomicAdd(&out[b * NCLASS + tid],
                  red[0][tid] + red[1][tid] + red[2][tid] + red[3][tid]);
}

// ---------------------------------------------------------------------------
extern "C" void kernel_launch(void* const* d_in, const int* in_sizes, int n_in,
                              void* d_out, int out_size, void* d_ws, size_t ws_size,
                              hipStream_t stream) {
    const int*   data = (const int*)d_in[0];
    const float* emb  = (const float*)d_in[1];
    const float* fw1  = (const float*)d_in[2];
    const float* fb1  = (const float*)d_in[3];
    const float* fw2  = (const float*)d_in[4];
    const float* fb2  = (const float*)d_in[5];
    const float* Wf   = (const float*)d_in[6];
    const float* bf   = (const float*)d_in[7];
    float* out = (float*)d_out;

    float* X      = (float*)d_ws;                         // 1,048,576 f
    float* CTpart = X + NB * NVEC * NDIM;                 // 8*64*17424 = 8,921,088 f
    float* CT     = CTpart + (size_t)MSC * NW * NB * CTSLOT;  // 1,115,136 f
    float* Zbuf   = CT + (size_t)NW * NB * CTSLOT;        // 66,048 f

    k_embed<<<dim3((NB * NVEC * NDIM) / 256), 256, 0, stream>>>(data, emb, bf, X, out);
    k_C<<<dim3(MSC, NB, NW), 256, 0, stream>>>(X, fw1, fb1, fw2, fb2, CTpart);
    k_Cred<<<dim3(4257), 256, 0, stream>>>(CTpart, CT);
    k_Z<<<dim3(4, NB), 192, 0, stream>>>(CT, Zbuf);
    k_out<<<dim3(16, NB), 256, 0, stream>>>(X, fw1, fb1, Zbuf, Wf, out);
}